// Round 19
// baseline (332.794 us; speedup 1.0000x reference)
//
#include <hip/hip_runtime.h>
#include <hip/hip_bf16.h>

typedef unsigned short u16;
typedef unsigned int u32;
typedef __attribute__((ext_vector_type(8))) short s8v;
typedef __attribute__((ext_vector_type(4))) float f4v;

#define HDIM 512
#define NNODE 16384
#define NB 15

__device__ __forceinline__ u16 f2bu(float x) {
  union { float f; u32 i; } v; v.f = x;
  u32 r = v.i + 0x7FFFu + ((v.i >> 16) & 1u);
  return (u16)(r >> 16);
}
__device__ __forceinline__ float bu2f(u16 u) {
  union { u32 i; float f; } v; v.i = ((u32)u) << 16;
  return v.f;
}
__device__ __forceinline__ u32 pk(float a, float b) {
  return (u32)f2bu(a) | ((u32)f2bu(b) << 16);
}
__device__ __forceinline__ float sigm(float x) {
  return __builtin_amdgcn_rcpf(1.f + __expf(-x));
}
__device__ __forceinline__ void gl16(const void* g, void* l) {
  __builtin_amdgcn_global_load_lds(
      (const __attribute__((address_space(1))) u32*)g,
      (__attribute__((address_space(3))) u32*)l, 16, 0, 0);
}
template<int N> __device__ __forceinline__ void wait_vm() {
  if constexpr (N == 0) asm volatile("s_waitcnt vmcnt(0)" ::: "memory");
  else if constexpr (N == 2) asm volatile("s_waitcnt vmcnt(2)" ::: "memory");
  else asm volatile("s_waitcnt vmcnt(4)" ::: "memory");
}

// ---------------- fused weight/bias conversion (21 segments) ----------------
__global__ __launch_bounds__(256) void k_cvt_all(
    const float* Wz_w, const float* Wr_w, const float* Wh_w, const float* Ui_w,
    const float* Ur_w, const float* W_w, const float* U_w, const float* Wo_w,
    const float* emb, const float* xtree,
    const float* Wz_b, const float* Wr_b, const float* Wh_b, const float* Ui_b,
    const float* W_b, const float* U_b,
    u16* wcat, u16* wz_h, u16* wh_h, u16* ui_h, u16* ur, u16* w_n, u16* u_n,
    u16* ccat, u16* wo, u16* emb_bf, u16* xt_bf, float* ebias, float* cbias) {
  int seg = blockIdx.y;
  const float* src = nullptr; u16* dst = nullptr;
  const float* fsrc = nullptr; float* fdst = nullptr;
  int R = 0, Cs = 0, c0 = 0, C = 0, fn = 0;
  switch (seg) {
    case 0:  src = Wz_w; dst = wcat;              R = 512;  Cs = 1024; c0 = 0;   C = 512; break;
    case 1:  src = Wr_w; dst = wcat + 512 * 512;  R = 512;  Cs = 512;  c0 = 0;   C = 512; break;
    case 2:  src = Wh_w; dst = wcat + 1024 * 512; R = 512;  Cs = 1024; c0 = 0;   C = 512; break;
    case 3:  src = Ui_w; dst = wcat + 1536 * 512; R = 512;  Cs = 1024; c0 = 0;   C = 512; break;
    case 4:  src = Wz_w; dst = wz_h;              R = 512;  Cs = 1024; c0 = 512; C = 512; break;
    case 5:  src = Wh_w; dst = wh_h;              R = 512;  Cs = 1024; c0 = 512; C = 512; break;
    case 6:  src = Ui_w; dst = ui_h;              R = 512;  Cs = 1024; c0 = 512; C = 512; break;
    case 7:  src = Ur_w; dst = ur;                R = 512;  Cs = 512;  c0 = 0;   C = 512; break;
    case 8:  src = W_w;  dst = w_n;               R = 512;  Cs = 640;  c0 = 0;   C = 512; break;
    case 9:  src = U_w;  dst = u_n;               R = 512;  Cs = 640;  c0 = 0;   C = 512; break;
    case 10: src = W_w;  dst = ccat;              R = 512;  Cs = 640;  c0 = 512; C = 128; break;
    case 11: src = U_w;  dst = ccat + 512 * 128;  R = 512;  Cs = 640;  c0 = 512; C = 128; break;
    case 12: src = Wo_w; dst = wo;                R = 1024; Cs = 512;  c0 = 0;   C = 512; break;
    case 13: src = emb;  dst = emb_bf;            R = 1024; Cs = 512;  c0 = 0;   C = 512; break;
    case 14: src = xtree; dst = xt_bf;            R = 256;  Cs = 128;  c0 = 0;   C = 128; break;
    case 15: fsrc = Wz_b; fdst = ebias;        fn = 512; break;
    case 16: fsrc = Wr_b; fdst = ebias + 512;  fn = 512; break;
    case 17: fsrc = Wh_b; fdst = ebias + 1024; fn = 512; break;
    case 18: fsrc = Ui_b; fdst = ebias + 1536; fn = 512; break;
    case 19: fsrc = W_b;  fdst = cbias;        fn = 512; break;
    case 20: fsrc = U_b;  fdst = cbias + 512;  fn = 512; break;
  }
  int i = blockIdx.x * 256 + threadIdx.x;
  if (fdst) { if (i < fn) fdst[i] = fsrc[i]; return; }
  int e0 = i * 8;
  if (e0 >= R * C) return;
  int r = e0 / C, c = e0 - r * C;
  const float* s = src + (size_t)r * Cs + c0 + c;
  float4 a = *reinterpret_cast<const float4*>(s);
  float4 b = *reinterpret_cast<const float4*>(s + 4);
  uint4 o = {pk(a.x, a.y), pk(a.z, a.w), pk(b.x, b.y), pk(b.z, b.w)};
  *reinterpret_cast<uint4*>(&dst[e0]) = o;
}

// ---------------- GEMM core: 128x128 tile, BK=32, 4-buf 3-deep pipeline ----
struct GP {
  const u16* A; const u16* B; int K; int lda;
  const float* gadd; int ldg; const int* gidx;
  const float* bias; const u16* shb;
  float* outf; u16* outh; int ldo;
};

template<int EP>
__device__ __forceinline__ void epi(int row, int col, float v, const GP& g) {
  if constexpr (EP == 0) {
    g.outf[(size_t)row * g.ldo + col] = v + (g.bias ? g.bias[col] : 0.f);
  } else if constexpr (EP == 3) {
    float pre = v + g.gadd[(size_t)g.gidx[row] * g.ldg + col];
    g.outh[(size_t)row * g.ldo + col] = f2bu(pre > 0.f ? pre : 0.f);
  } else {  // EP == 4: plain bf16 store
    g.outh[(size_t)row * g.ldo + col] = f2bu(v);
  }
}

__device__ __forceinline__ void swz_tile(int nx, int ny, int& m0, int& n0) {
  int orig = blockIdx.y * nx + blockIdx.x;
  int q = (nx * ny) >> 3;
  int tile = (orig & 7) * q + (orig >> 3);
  n0 = (tile % nx) * 128;
  m0 = (tile / nx) * 128;
}

template<int EP, int KV>
__device__ void gemm_core(const GP& g, u16* AsB, u16* BsB, int m0, int n0) {
  const int tid = threadIdx.x, lane = tid & 63, w = tid >> 6;  // 8 waves
  const int wm = (w >> 2) * 64, wn = (w & 3) * 32;

  const int sr = tid >> 2, sc = (tid & 3) ^ ((sr >> 1) & 3);
  const u16* gA = g.A + (size_t)(m0 + sr) * g.lda + sc * 8;
  const u16* gB = g.B + (size_t)(n0 + sr) * KV + sc * 8;
  const int ls = tid * 8;

  f4v acc[4][2];
  f4v z4 = {0.f, 0.f, 0.f, 0.f};
#pragma unroll
  for (int a = 0; a < 4; a++) { acc[a][0] = z4; acc[a][1] = z4; }

  constexpr int T = KV / 32;
  auto STAGE = [&](int t) {
    int buf = (t & 3) * 4096;
    gl16(gA + t * 32, AsB + buf + ls);
    gl16(gB + t * 32, BsB + buf + ls);
  };
  STAGE(0); STAGE(1); STAGE(2);

#pragma unroll
  for (int t = 0; t < T; t++) {
    if (t < T - 2) wait_vm<4>();
    else if (t == T - 2) wait_vm<2>();
    else wait_vm<0>();
    __builtin_amdgcn_s_barrier();
    asm volatile("" ::: "memory");
    if (t + 3 < T) STAGE(t + 3);
    const u16* as = AsB + (t & 3) * 4096;
    const u16* bs = BsB + (t & 3) * 4096;
    s8v af[4], bf[2];
    int cc = lane >> 4;
#pragma unroll
    for (int i = 0; i < 4; i++) {
      int R = wm + i * 16 + (lane & 15);
      af[i] = *reinterpret_cast<const s8v*>(
          &as[R * 32 + (cc ^ ((R >> 1) & 3)) * 8]);
    }
#pragma unroll
    for (int i = 0; i < 2; i++) {
      int C = wn + i * 16 + (lane & 15);
      bf[i] = *reinterpret_cast<const s8v*>(
          &bs[C * 32 + (cc ^ ((C >> 1) & 3)) * 8]);
    }
    __builtin_amdgcn_s_setprio(1);
#pragma unroll
    for (int mi = 0; mi < 4; mi++)
#pragma unroll
      for (int ni = 0; ni < 2; ni++)
        acc[mi][ni] = __builtin_amdgcn_mfma_f32_16x16x32_bf16(
            af[mi], bf[ni], acc[mi][ni], 0, 0, 0);
    __builtin_amdgcn_s_setprio(0);
  }
#pragma unroll
  for (int mi = 0; mi < 4; mi++)
#pragma unroll
    for (int ni = 0; ni < 2; ni++)
#pragma unroll
      for (int r = 0; r < 4; r++) {
        int row = m0 + wm + mi * 16 + (lane >> 4) * 4 + r;
        int col = n0 + wn + ni * 16 + (lane & 15);
        epi<EP>(row, col, acc[mi][ni][r], g);
      }
}

// 2-buffer depth-1 variant (32KB total LDS) for occupancy-sensitive mixes.
template<int EP, int KV>
__device__ void gemm_2buf(const GP& g, u16* AsB, u16* BsB, int m0, int n0) {
  const int tid = threadIdx.x, lane = tid & 63, w = tid >> 6;
  const int wm = (w >> 2) * 64, wn = (w & 3) * 32;
  const int sr = tid >> 2, sc = (tid & 3) ^ ((sr >> 1) & 3);
  const u16* gA = g.A + (size_t)(m0 + sr) * g.lda + sc * 8;
  const u16* gB = g.B + (size_t)(n0 + sr) * KV + sc * 8;
  const int ls = tid * 8;

  f4v acc[4][2];
  f4v z4 = {0.f, 0.f, 0.f, 0.f};
#pragma unroll
  for (int a = 0; a < 4; a++) { acc[a][0] = z4; acc[a][1] = z4; }

  constexpr int T = KV / 32;
  auto STAGE = [&](int t) {
    int buf = (t & 1) * 4096;
    gl16(gA + t * 32, AsB + buf + ls);
    gl16(gB + t * 32, BsB + buf + ls);
  };
  STAGE(0);
#pragma unroll
  for (int t = 0; t < T; t++) {
    __syncthreads();  // drains vmcnt: buf[t&1] ready, buf[t&1^1] free
    if (t + 1 < T) STAGE(t + 1);
    const u16* as = AsB + (t & 1) * 4096;
    const u16* bs = BsB + (t & 1) * 4096;
    s8v af[4], bf[2];
    int cc = lane >> 4;
#pragma unroll
    for (int i = 0; i < 4; i++) {
      int R = wm + i * 16 + (lane & 15);
      af[i] = *reinterpret_cast<const s8v*>(
          &as[R * 32 + (cc ^ ((R >> 1) & 3)) * 8]);
    }
#pragma unroll
    for (int i = 0; i < 2; i++) {
      int C = wn + i * 16 + (lane & 15);
      bf[i] = *reinterpret_cast<const s8v*>(
          &bs[C * 32 + (cc ^ ((C >> 1) & 3)) * 8]);
    }
    __builtin_amdgcn_s_setprio(1);
#pragma unroll
    for (int mi = 0; mi < 4; mi++)
#pragma unroll
      for (int ni = 0; ni < 2; ni++)
        acc[mi][ni] = __builtin_amdgcn_mfma_f32_16x16x32_bf16(
            af[mi], bf[ni], acc[mi][ni], 0, 0, 0);
    __builtin_amdgcn_s_setprio(0);
  }
#pragma unroll
  for (int mi = 0; mi < 4; mi++)
#pragma unroll
    for (int ni = 0; ni < 2; ni++)
#pragma unroll
      for (int r = 0; r < 4; r++) {
        int row = m0 + wm + mi * 16 + (lane >> 4) * 4 + r;
        int col = n0 + wn + ni * 16 + (lane & 15);
        epi<EP>(row, col, acc[mi][ni][r], g);
      }
}

template<int EPa, int EPb, int KV>
__global__ __launch_bounds__(512, 4) void k_pair(GP a, GP b) {
  __shared__ u16 As[4 * 4096], Bs[4 * 4096];
  int m0, n0;
  swz_tile(gridDim.x, gridDim.y, m0, n0);
  if (blockIdx.z == 0) gemm_core<EPa, KV>(a, As, Bs, m0, n0);
  else gemm_core<EPb, KV>(b, As, Bs, m0, n0);
}

// ---------------- mixed dispatch: tables + R2 (f32-A reg-staged, emits H_bf)
// blocks [0,128): ge tiles  [128,144): gc tiles
// blocks [144, 144+2048): R2 tiles. R2 A-path: load H_msg f32 -> cvt bf16 in
// regs -> swizzled ds_write; n0==0 blocks also store the tile to H_bf
// (replaces the old cvtH pass). 4 adjacent blocks share an A-panel (L2/L3).
__global__ __launch_bounds__(512, 4) void k_mixR(
    const float* __restrict__ Hf, u16* __restrict__ Hb, u16* __restrict__ R2,
    const u16* __restrict__ ur, GP ge, GP gc) {
  __shared__ u16 S[16384];  // 32 KB: A 2x4096 | B 2x4096
  int id = blockIdx.x;
  if (id < 128) {
    gemm_2buf<0, 512>(ge, S, S + 8192, (id >> 4) * 128, (id & 15) * 128);
    return;
  }
  if (id < 144) {
    int t = id - 128;
    gemm_2buf<0, 128>(gc, S, S + 8192, (t >> 3) * 128, (t & 7) * 128);
    return;
  }
  const int rid = id - 144;
  const int m0 = (rid >> 2) * 128, n0 = (rid & 3) * 128;
  const int tid = threadIdx.x, lane = tid & 63, w = tid >> 6;
  const int wm = (w >> 2) * 64, wn = (w & 3) * 32;
  const int sr = tid >> 2;
  const int c4 = tid & 3;                          // A f32 col group (plain)
  const int scB = c4 ^ ((sr >> 1) & 3);            // B source pre-swizzle
  const float* gAf = Hf + (size_t)(m0 + sr) * HDIM + c4 * 8;
  const u16* gB = ur + (size_t)(n0 + sr) * HDIM + scB * 8;
  u16* hOut = (n0 == 0) ? Hb + (size_t)(m0 + sr) * HDIM + c4 * 8 : nullptr;
  u16* AsB = S;
  u16* BsB = S + 8192;
  const int lsB = tid * 8;
  const int lsA = sr * 32 + (c4 ^ ((sr >> 1) & 3)) * 8;  // swizzled A dest

  f4v acc[4][2];
  f4v z4 = {0.f, 0.f, 0.f, 0.f};
#pragma unroll
  for (int a = 0; a < 4; a++) { acc[a][0] = z4; acc[a][1] = z4; }

  {
    float4 a0 = *reinterpret_cast<const float4*>(gAf);
    float4 a1 = *reinterpret_cast<const float4*>(gAf + 4);
    gl16(gB, BsB + lsB);
    uint4 v = {pk(a0.x, a0.y), pk(a0.z, a0.w), pk(a1.x, a1.y), pk(a1.z, a1.w)};
    *reinterpret_cast<uint4*>(&AsB[lsA]) = v;
    if (hOut) *reinterpret_cast<uint4*>(hOut) = v;
  }
  __syncthreads();
#pragma unroll
  for (int t = 0; t < 16; t++) {
    float4 na0, na1;
    if (t + 1 < 16) {
      na0 = *reinterpret_cast<const float4*>(gAf + (t + 1) * 32);
      na1 = *reinterpret_cast<const float4*>(gAf + (t + 1) * 32 + 4);
      gl16(gB + (t + 1) * 32, BsB + ((t + 1) & 1) * 4096 + lsB);
    }
    const u16* as = AsB + (t & 1) * 4096;
    const u16* bs = BsB + (t & 1) * 4096;
    s8v af[4], bf[2];
    int cc = lane >> 4;
#pragma unroll
    for (int i = 0; i < 4; i++) {
      int R = wm + i * 16 + (lane & 15);
      af[i] = *reinterpret_cast<const s8v*>(
          &as[R * 32 + (cc ^ ((R >> 1) & 3)) * 8]);
    }
#pragma unroll
    for (int i = 0; i < 2; i++) {
      int C = wn + i * 16 + (lane & 15);
      bf[i] = *reinterpret_cast<const s8v*>(
          &bs[C * 32 + (cc ^ ((C >> 1) & 3)) * 8]);
    }
    __builtin_amdgcn_s_setprio(1);
#pragma unroll
    for (int mi = 0; mi < 4; mi++)
#pragma unroll
      for (int ni = 0; ni < 2; ni++)
        acc[mi][ni] = __builtin_amdgcn_mfma_f32_16x16x32_bf16(
            af[mi], bf[ni], acc[mi][ni], 0, 0, 0);
    __builtin_amdgcn_s_setprio(0);
    if (t + 1 < 16) {
      uint4 v = {pk(na0.x, na0.y), pk(na0.z, na0.w),
                 pk(na1.x, na1.y), pk(na1.z, na1.w)};
      *reinterpret_cast<uint4*>(&AsB[((t + 1) & 1) * 4096 + lsA]) = v;
      if (hOut) *reinterpret_cast<uint4*>(hOut + (size_t)(t + 1) * 32) = v;
      __syncthreads();
    }
  }
#pragma unroll
  for (int mi = 0; mi < 4; mi++)
#pragma unroll
    for (int ni = 0; ni < 2; ni++)
#pragma unroll
      for (int r = 0; r < 4; r++) {
        int row = m0 + wm + mi * 16 + (lane >> 4) * 4 + r;
        int col = n0 + wn + ni * 16 + (lane & 15);
        R2[(size_t)row * HDIM + col] = f2bu(acc[mi][ni][r]);
      }
}

// ---------------- fused z+new_h (z==0) + stop_h GEMM (z==1) -----------------
__global__ __launch_bounds__(512, 4) void k_znp(
    const u16* __restrict__ sumh, const u16* __restrict__ sg,
    const u16* __restrict__ Wz, const u16* __restrict__ Wh,
    const float* __restrict__ E_z, const float* __restrict__ E_h, int ldg,
    const int* __restrict__ gidx, u16* __restrict__ newh, GP gs) {
  __shared__ u16 S[32768];  // 64 KB shared between the two block roles
  int m0, n0;
  swz_tile(gridDim.x, gridDim.y, m0, n0);
  if (blockIdx.z == 1) { gemm_core<3, 512>(gs, S, S + 16384, m0, n0); return; }
  const int tid = threadIdx.x, lane = tid & 63, w = tid >> 6;
  const int wm = (w >> 2) * 64, wn = (w & 3) * 32;

  const int sr = tid >> 2, sc = (tid & 3) ^ ((sr >> 1) & 3);
  const u16* gA[2] = {sumh + (size_t)(m0 + sr) * HDIM + sc * 8,
                      sg + (size_t)(m0 + sr) * HDIM + sc * 8};
  const u16* gB[2] = {Wz + (size_t)(n0 + sr) * HDIM + sc * 8,
                      Wh + (size_t)(n0 + sr) * HDIM + sc * 8};
  const int ls = tid * 8;
  u16* AsB = S;            // 4 bufs x 4096 u16
  u16* BsB = S + 16384;    // 4 bufs x 4096 u16
  auto STAGE = [&](int s) {
    int p = s & 1, k0 = (s >> 1) * 32;
    int buf = (s & 3) * 4096;
    gl16(gA[p] + k0, AsB + buf + ls);
    gl16(gB[p] + k0, BsB + buf + ls);
  };

  f4v az[4][2], ah[4][2];
  f4v z4 = {0.f, 0.f, 0.f, 0.f};
#pragma unroll
  for (int a = 0; a < 4; a++) {
    az[a][0] = z4; az[a][1] = z4; ah[a][0] = z4; ah[a][1] = z4;
  }

  STAGE(0); STAGE(1); STAGE(2);
#pragma unroll
  for (int s = 0; s < 32; s++) {
    if (s < 30) wait_vm<4>();
    else if (s == 30) wait_vm<2>();
    else wait_vm<0>();
    __builtin_amdgcn_s_barrier();
    asm volatile("" ::: "memory");
    if (s + 3 < 32) STAGE(s + 3);
    const u16* as = AsB + (s & 3) * 4096;
    const u16* bs = BsB + (s & 3) * 4096;
    s8v af[4], bf[2];
    int cc = lane >> 4;
#pragma unroll
    for (int i = 0; i < 4; i++) {
      int R = wm + i * 16 + (lane & 15);
      af[i] = *reinterpret_cast<const s8v*>(
          &as[R * 32 + (cc ^ ((R >> 1) & 3)) * 8]);
    }
#pragma unroll
    for (int i = 0; i < 2; i++) {
      int C = wn + i * 16 + (lane & 15);
      bf[i] = *reinterpret_cast<const s8v*>(
          &bs[C * 32 + (cc ^ ((C >> 1) & 3)) * 8]);
    }
    f4v (&acc)[4][2] = (s & 1) ? ah : az;  // s is compile-time (unrolled)
    __builtin_amdgcn_s_setprio(1);
#pragma unroll
    for (int mi = 0; mi < 4; mi++)
#pragma unroll
      for (int ni = 0; ni < 2; ni++)
        acc[mi][ni] = __builtin_amdgcn_mfma_f32_16x16x32_bf16(
            af[mi], bf[ni], acc[mi][ni], 0, 0, 0);
    __builtin_amdgcn_s_setprio(0);
  }
#pragma unroll
  for (int mi = 0; mi < 4; mi++)
#pragma unroll
    for (int r = 0; r < 4; r++) {
      int row = m0 + wm + mi * 16 + (lane >> 4) * 4 + r;
      int xid = gidx[row];
      const float* ez = E_z + (size_t)xid * ldg;
      const float* eh = E_h + (size_t)xid * ldg;
#pragma unroll
      for (int ni = 0; ni < 2; ni++) {
        int col = n0 + wn + ni * 16 + (lane & 15);
        float zv = sigm(az[mi][ni][r] + ez[col]);
        float pre = tanhf(ah[mi][ni][r] + eh[col]);
        float sh = bu2f(sumh[(size_t)row * HDIM + col]);
        newh[(size_t)row * HDIM + col] = f2bu((1.f - zv) * sh + zv * pre);
      }
    }
}

// ---------------- fused gather: 4 nodes/block, 64 thr/node, uint4 loads -----
__global__ __launch_bounds__(256) void k_gsr(
    const u16* __restrict__ Hb, const u16* __restrict__ R2,
    const float* __restrict__ E_r, int ldg, const int* __restrict__ x_ids,
    const int* __restrict__ nei_idx, const int* __restrict__ nei_mask,
    const int* __restrict__ o_idx, const int* __restrict__ o_mask,
    u16* __restrict__ sum_h_bf, u16* __restrict__ sg_bf,
    u16* __restrict__ cur_o_bf) {
  int t = threadIdx.x;
  int nd = t >> 6, lane = t & 63;
  int n = blockIdx.x * 4 + nd;
  __shared__ int sidx[4][NB], smsk[4][NB], soid[4][NB], somk[4][NB];
  __shared__ int sx[4];
  if (t < 60) {
    int nn = t / 15, k = t - nn * 15;
    size_t gofs = (size_t)(blockIdx.x * 4 + nn) * NB + k;
    sidx[nn][k] = nei_idx[gofs];
    smsk[nn][k] = nei_mask[gofs];
  } else if (t >= 64 && t < 124) {
    int tt = t - 64;
    int nn = tt / 15, k = tt - nn * 15;
    size_t gofs = (size_t)(blockIdx.x * 4 + nn) * NB + k;
    soid[nn][k] = o_idx[gofs];
    somk[nn][k] = o_mask[gofs];
  } else if (t >= 128 && t < 132) {
    sx[t - 128] = x_ids[blockIdx.x * 4 + (t - 128)];
  }
  __syncthreads();
  int c = lane * 8;
  const float* er = E_r + (size_t)sx[nd] * ldg + c;
  float4 e0 = *reinterpret_cast<const float4*>(er);
  float4 e1 = *reinterpret_cast<const float4*>(er + 4);
  float ev[8] = {e0.x, e0.y, e0.z, e0.w, e1.x, e1.y, e1.z, e1.w};
  float s[8], gg[8], oo[8];
#pragma unroll
  for (int i = 0; i < 8; i++) { s[i] = 0.f; gg[i] = 0.f; oo[i] = 0.f; }
#pragma unroll
  for (int k = 0; k < NB; k++) {
    if (smsk[nd][k]) {
      size_t rb = (size_t)sidx[nd][k] * HDIM + c;
      uint4 hv = *reinterpret_cast<const uint4*>(Hb + rb);
      uint4 rv = *reinterpret_cast<const uint4*>(R2 + rb);
      u32 ha[4] = {hv.x, hv.y, hv.z, hv.w};
      u32 ra[4] = {rv.x, rv.y, rv.z, rv.w};
#pragma unroll
      for (int p = 0; p < 4; p++) {
        float h0 = bu2f((u16)ha[p]), h1 = bu2f((u16)(ha[p] >> 16));
        s[p * 2] += h0; s[p * 2 + 1] += h1;
        gg[p * 2] += sigm(bu2f((u16)ra[p]) + ev[p * 2]) * h0;
        gg[p * 2 + 1] += sigm(bu2f((u16)(ra[p] >> 16)) + ev[p * 2 + 1]) * h1;
      }
    }
    if (somk[nd][k]) {
      uint4 ov = *reinterpret_cast<const uint4*>(
          Hb + (size_t)soid[nd][k] * HDIM + c);
      u32 oa[4] = {ov.x, ov.y, ov.z, ov.w};
#pragma unroll
      for (int p = 0; p < 4; p++) {
        oo[p * 2] += bu2f((u16)oa[p]);
        oo[p * 2 + 1] += bu2f((u16)(oa[p] >> 16));
      }
    }
  }
  size_t b = (size_t)n * HDIM + c;
  uint4 ps = {pk(s[0], s[1]), pk(s[2], s[3]), pk(s[4], s[5]), pk(s[6], s[7])};
  uint4 pg = {pk(gg[0], gg[1]), pk(gg[2], gg[3]), pk(gg[4], gg[5]), pk(gg[6], gg[7])};
  uint4 po = {pk(oo[0], oo[1]), pk(oo[2], oo[3]), pk(oo[4], oo[5]), pk(oo[6], oo[7])};
  *reinterpret_cast<uint4*>(&sum_h_bf[b]) = ps;
  *reinterpret_cast<uint4*>(&sg_bf[b]) = pg;
  *reinterpret_cast<uint4*>(&cur_o_bf[b]) = po;
}

// ---------------- word GEMM (z==0) + stop scores (z==1) ---------------------
__global__ __launch_bounds__(512, 4) void k_wordstop(
    GP wgp, const u16* __restrict__ shid, const float* __restrict__ Uo_w,
    const float* __restrict__ Uo_b, float* __restrict__ out) {
  __shared__ u16 As[4 * 4096], Bs[4 * 4096];
  if (blockIdx.z == 0) {
    int m0, n0;
    swz_tile(gridDim.x, gridDim.y, m0, n0);
    gemm_core<0, 512>(wgp, As, Bs, m0, n0);
    return;
  }
  int b = blockIdx.y * gridDim.x + blockIdx.x;  // 0..1023
  int wv = threadIdx.x >> 6, lane = threadIdx.x & 63;
#pragma unroll
  for (int i = 0; i < 2; i++) {
    int n = b * 16 + wv * 2 + i;
    const u16* row = shid + (size_t)n * HDIM + lane * 8;
    const float* uw = Uo_w + lane * 8;
    uint4 v = *reinterpret_cast<const uint4*>(row);
    float4 u0 = *reinterpret_cast<const float4*>(uw);
    float4 u1 = *reinterpret_cast<const float4*>(uw + 4);
    float s = bu2f((u16)v.x) * u0.x + bu2f((u16)(v.x >> 16)) * u0.y +
              bu2f((u16)v.y) * u0.z + bu2f((u16)(v.y >> 16)) * u0.w +
              bu2f((u16)v.z) * u1.x + bu2f((u16)(v.z >> 16)) * u1.y +
              bu2f((u16)v.w) * u1.z + bu2f((u16)(v.w >> 16)) * u1.w;
#pragma unroll
    for (int off = 32; off; off >>= 1) s += __shfl_xor(s, off, 64);
    if (lane == 0) out[(size_t)n * 1025 + 1024] = s + Uo_b[0];
  }
}

// ---------------- host ----------------
extern "C" void kernel_launch(void* const* d_in, const int* in_sizes, int n_in,
                              void* d_out, int out_size, void* d_ws, size_t ws_size,
                              hipStream_t stream) {
  const int* x_ids = (const int*)d_in[0];
  const int* contexts = (const int*)d_in[1];
  const int* nei_idx = (const int*)d_in[2];
  const int* nei_mask = (const int*)d_in[3];
  const int* o_idx = (const int*)d_in[4];
  const int* o_mask = (const int*)d_in[5];
  const float* H_msg = (const float*)d_in[6];
  const float* xtree = (const float*)d_in[7];
  const float* emb = (const float*)d_in[8];
  const float* Wz_w = (const float*)d_in[9];  const float* Wz_b = (const float*)d_in[10];
  const float* Wr_w = (const float*)d_in[11]; const float* Wr_b = (const float*)d_in[12];
  const float* Ur_w = (const float*)d_in[13];
  const float* Wh_w = (const float*)d_in[14]; const float* Wh_b = (const float*)d_in[15];
  const float* W_w  = (const float*)d_in[16]; const float* W_b  = (const float*)d_in[17];
  const float* Wo_w = (const float*)d_in[18]; const float* Wo_b = (const float*)d_in[19];
  const float* Ui_w = (const float*)d_in[20]; const float* Ui_b = (const float*)d_in[21];
  const float* U_w  = (const float*)d_in[22]; const float* U_b  = (const float*)d_in[23];
  const float* Uo_w = (const float*)d_in[24]; const float* Uo_b = (const float*)d_in[25];
  float* out = (float*)d_out;
  const int M = 65536;

  char* base = (char*)d_ws;
  size_t ofs = 0;
  auto alloc = [&](size_t bytes) -> char* {
    char* p = base + ofs;
    ofs = (ofs + bytes + 255) & ~(size_t)255;
    return p;
  };
  u16* wcat  = (u16*)alloc((size_t)2048 * 512 * 2);
  u16* wz_h  = (u16*)alloc(512 * 512 * 2);
  u16* wh_h  = (u16*)alloc(512 * 512 * 2);
  u16* ui_h  = (u16*)alloc(512 * 512 * 2);
  u16* ur    = (u16*)alloc(512 * 512 * 2);
  u16* w_n   = (u16*)alloc(512 * 512 * 2);
  u16* u_n   = (u16*)alloc(512 * 512 * 2);
  u16* ccat  = (u16*)alloc(1024 * 128 * 2);
  u16* wo    = (u16*)alloc(1024 * 512 * 2);
  u16* emb_bf = (u16*)alloc(1024 * 512 * 2);
  u16* xt_bf  = (u16*)alloc(256 * 128 * 2);
  float* ebias = (float*)alloc(2048 * 4);
  float* cbias = (float*)alloc(1024 * 4);
  float* E_cat = (float*)alloc((size_t)1024 * 2048 * 4);
  float* C_cat = (float*)alloc((size_t)256 * 1024 * 4);
  u16* H_bf = (u16*)alloc((size_t)M * HDIM * 2);
  u16* R2   = (u16*)alloc((size_t)M * HDIM * 2);
  u16* sum_h_bf = (u16*)alloc((size_t)NNODE * HDIM * 2);
  u16* cur_o_bf = (u16*)alloc((size_t)NNODE * HDIM * 2);
  u16* sg_bf    = (u16*)alloc((size_t)NNODE * HDIM * 2);
  u16* newh_bf  = (u16*)alloc((size_t)NNODE * HDIM * 2);
  u16* whid_bf  = (u16*)alloc((size_t)NNODE * HDIM * 2);
  u16* stoph_bf = (u16*)alloc((size_t)NNODE * HDIM * 2);
  u16* shid_bf  = (u16*)alloc((size_t)NNODE * HDIM * 2);

  k_cvt_all<<<dim3(256, 21), dim3(256), 0, stream>>>(
      Wz_w, Wr_w, Wh_w, Ui_w, Ur_w, W_w, U_w, Wo_w, emb, xtree,
      Wz_b, Wr_b, Wh_b, Ui_b, W_b, U_b,
      wcat, wz_h, wh_h, ui_h, ur, w_n, u_n, ccat, wo, emb_bf, xt_bf,
      ebias, cbias);

  // tables + R2 (f32-A reg-staged GEMM that also emits H_bf) in one dispatch
  GP ge{emb_bf, wcat, 512, 512, nullptr, 0, nullptr, ebias, nullptr,
        E_cat, nullptr, 2048};
  GP gc{xt_bf, ccat, 128, 128, nullptr, 0, nullptr, cbias, nullptr,
        C_cat, nullptr, 1024};
  k_mixR<<<dim3(144 + 2048), dim3(512), 0, stream>>>(
      H_msg, H_bf, R2, ur, ge, gc);

  // fused gather: sum_h, sg = sum sigmoid(r2+E_r)*h, cur_o
  k_gsr<<<dim3(NNODE / 4), dim3(256), 0, stream>>>(
      H_bf, R2, E_cat + 512, 2048, x_ids, nei_idx, nei_mask, o_idx, o_mask,
      sum_h_bf, sg_bf, cur_o_bf);

  // z+new_h (z==0) and stop_h (z==1) in one dispatch
  GP gs{cur_o_bf, ui_h, 512, 512, E_cat + 1536, 2048, x_ids, nullptr, nullptr,
        nullptr, stoph_bf, 512};
  k_znp<<<dim3(4, 128, 2), dim3(512), 0, stream>>>(
      sum_h_bf, sg_bf, wz_h, wh_h, E_cat, E_cat + 1024, 2048, x_ids,
      newh_bf, gs);

  // w_hid + s_hid paired (both EP3)
  GP gw{newh_bf, w_n, 512, 512, C_cat, 1024, contexts, nullptr, nullptr,
        nullptr, whid_bf, 512};
  GP gu{stoph_bf, u_n, 512, 512, C_cat + 512, 1024, contexts, nullptr, nullptr,
        nullptr, shid_bf, 512};
  k_pair<3, 3, 512><<<dim3(4, 128, 2), dim3(512), 0, stream>>>(gw, gu);

  // word scores (z==0) + stop scores (z==1)
  GP gword{whid_bf, wo, 512, 512, nullptr, 0, nullptr, Wo_b, nullptr,
           out, nullptr, 1025};
  k_wordstop<<<dim3(8, 128, 2), dim3(512), 0, stream>>>(
      gword, shid_bf, Uo_w, Uo_b, out);
}

// Round 20
// 294.230 us; speedup vs baseline: 1.1311x; 1.1311x over previous
//
#include <hip/hip_runtime.h>
#include <hip/hip_bf16.h>

typedef unsigned short u16;
typedef unsigned int u32;
typedef __attribute__((ext_vector_type(8))) short s8v;
typedef __attribute__((ext_vector_type(4))) float f4v;

#define HDIM 512
#define NNODE 16384
#define NB 15

__device__ __forceinline__ u16 f2bu(float x) {
  union { float f; u32 i; } v; v.f = x;
  u32 r = v.i + 0x7FFFu + ((v.i >> 16) & 1u);
  return (u16)(r >> 16);
}
__device__ __forceinline__ float bu2f(u16 u) {
  union { u32 i; float f; } v; v.i = ((u32)u) << 16;
  return v.f;
}
__device__ __forceinline__ u32 pk(float a, float b) {
  return (u32)f2bu(a) | ((u32)f2bu(b) << 16);
}
__device__ __forceinline__ float sigm(float x) {
  return __builtin_amdgcn_rcpf(1.f + __expf(-x));
}
__device__ __forceinline__ void gl16(const void* g, void* l) {
  __builtin_amdgcn_global_load_lds(
      (const __attribute__((address_space(1))) u32*)g,
      (__attribute__((address_space(3))) u32*)l, 16, 0, 0);
}
template<int N> __device__ __forceinline__ void wait_vm() {
  if constexpr (N == 0) asm volatile("s_waitcnt vmcnt(0)" ::: "memory");
  else if constexpr (N == 2) asm volatile("s_waitcnt vmcnt(2)" ::: "memory");
  else asm volatile("s_waitcnt vmcnt(4)" ::: "memory");
}

// ---------------- fused weight/bias conversion (21 segments) ----------------
__global__ __launch_bounds__(256) void k_cvt_all(
    const float* Wz_w, const float* Wr_w, const float* Wh_w, const float* Ui_w,
    const float* Ur_w, const float* W_w, const float* U_w, const float* Wo_w,
    const float* emb, const float* xtree,
    const float* Wz_b, const float* Wr_b, const float* Wh_b, const float* Ui_b,
    const float* W_b, const float* U_b,
    u16* wcat, u16* wz_h, u16* wh_h, u16* ui_h, u16* ur, u16* w_n, u16* u_n,
    u16* ccat, u16* wo, u16* emb_bf, u16* xt_bf, float* ebias, float* cbias) {
  int seg = blockIdx.y;
  const float* src = nullptr; u16* dst = nullptr;
  const float* fsrc = nullptr; float* fdst = nullptr;
  int R = 0, Cs = 0, c0 = 0, C = 0, fn = 0;
  switch (seg) {
    case 0:  src = Wz_w; dst = wcat;              R = 512;  Cs = 1024; c0 = 0;   C = 512; break;
    case 1:  src = Wr_w; dst = wcat + 512 * 512;  R = 512;  Cs = 512;  c0 = 0;   C = 512; break;
    case 2:  src = Wh_w; dst = wcat + 1024 * 512; R = 512;  Cs = 1024; c0 = 0;   C = 512; break;
    case 3:  src = Ui_w; dst = wcat + 1536 * 512; R = 512;  Cs = 1024; c0 = 0;   C = 512; break;
    case 4:  src = Wz_w; dst = wz_h;              R = 512;  Cs = 1024; c0 = 512; C = 512; break;
    case 5:  src = Wh_w; dst = wh_h;              R = 512;  Cs = 1024; c0 = 512; C = 512; break;
    case 6:  src = Ui_w; dst = ui_h;              R = 512;  Cs = 1024; c0 = 512; C = 512; break;
    case 7:  src = Ur_w; dst = ur;                R = 512;  Cs = 512;  c0 = 0;   C = 512; break;
    case 8:  src = W_w;  dst = w_n;               R = 512;  Cs = 640;  c0 = 0;   C = 512; break;
    case 9:  src = U_w;  dst = u_n;               R = 512;  Cs = 640;  c0 = 0;   C = 512; break;
    case 10: src = W_w;  dst = ccat;              R = 512;  Cs = 640;  c0 = 512; C = 128; break;
    case 11: src = U_w;  dst = ccat + 512 * 128;  R = 512;  Cs = 640;  c0 = 512; C = 128; break;
    case 12: src = Wo_w; dst = wo;                R = 1024; Cs = 512;  c0 = 0;   C = 512; break;
    case 13: src = emb;  dst = emb_bf;            R = 1024; Cs = 512;  c0 = 0;   C = 512; break;
    case 14: src = xtree; dst = xt_bf;            R = 256;  Cs = 128;  c0 = 0;   C = 128; break;
    case 15: fsrc = Wz_b; fdst = ebias;        fn = 512; break;
    case 16: fsrc = Wr_b; fdst = ebias + 512;  fn = 512; break;
    case 17: fsrc = Wh_b; fdst = ebias + 1024; fn = 512; break;
    case 18: fsrc = Ui_b; fdst = ebias + 1536; fn = 512; break;
    case 19: fsrc = W_b;  fdst = cbias;        fn = 512; break;
    case 20: fsrc = U_b;  fdst = cbias + 512;  fn = 512; break;
  }
  int i = blockIdx.x * 256 + threadIdx.x;
  if (fdst) { if (i < fn) fdst[i] = fsrc[i]; return; }
  int e0 = i * 8;
  if (e0 >= R * C) return;
  int r = e0 / C, c = e0 - r * C;
  const float* s = src + (size_t)r * Cs + c0 + c;
  float4 a = *reinterpret_cast<const float4*>(s);
  float4 b = *reinterpret_cast<const float4*>(s + 4);
  uint4 o = {pk(a.x, a.y), pk(a.z, a.w), pk(b.x, b.y), pk(b.z, b.w)};
  *reinterpret_cast<uint4*>(&dst[e0]) = o;
}

// ---------------- GEMM core: 128x128 tile, BK=32, 4-buf 3-deep pipeline ----
struct GP {
  const u16* A; const u16* B; int K; int lda;
  const float* gadd; int ldg; const int* gidx;
  const float* bias; const u16* shb;
  float* outf; u16* outh; int ldo;
};

template<int EP>
__device__ __forceinline__ void epi(int row, int col, float v, const GP& g) {
  if constexpr (EP == 0) {
    g.outf[(size_t)row * g.ldo + col] = v + (g.bias ? g.bias[col] : 0.f);
  } else if constexpr (EP == 3) {
    float pre = v + g.gadd[(size_t)g.gidx[row] * g.ldg + col];
    g.outh[(size_t)row * g.ldo + col] = f2bu(pre > 0.f ? pre : 0.f);
  } else {  // EP == 4: plain bf16 store
    g.outh[(size_t)row * g.ldo + col] = f2bu(v);
  }
}

__device__ __forceinline__ void swz_tile(int nx, int ny, int& m0, int& n0) {
  int orig = blockIdx.y * nx + blockIdx.x;
  int q = (nx * ny) >> 3;
  int tile = (orig & 7) * q + (orig >> 3);
  n0 = (tile % nx) * 128;
  m0 = (tile / nx) * 128;
}

template<int EP, int KV>
__device__ void gemm_core(const GP& g, u16* AsB, u16* BsB, int m0, int n0) {
  const int tid = threadIdx.x, lane = tid & 63, w = tid >> 6;  // 8 waves
  const int wm = (w >> 2) * 64, wn = (w & 3) * 32;

  const int sr = tid >> 2, sc = (tid & 3) ^ ((sr >> 1) & 3);
  const u16* gA = g.A + (size_t)(m0 + sr) * g.lda + sc * 8;
  const u16* gB = g.B + (size_t)(n0 + sr) * KV + sc * 8;
  const int ls = tid * 8;

  f4v acc[4][2];
  f4v z4 = {0.f, 0.f, 0.f, 0.f};
#pragma unroll
  for (int a = 0; a < 4; a++) { acc[a][0] = z4; acc[a][1] = z4; }

  constexpr int T = KV / 32;
  auto STAGE = [&](int t) {
    int buf = (t & 3) * 4096;
    gl16(gA + t * 32, AsB + buf + ls);
    gl16(gB + t * 32, BsB + buf + ls);
  };
  STAGE(0); STAGE(1); STAGE(2);

#pragma unroll
  for (int t = 0; t < T; t++) {
    if (t < T - 2) wait_vm<4>();
    else if (t == T - 2) wait_vm<2>();
    else wait_vm<0>();
    __builtin_amdgcn_s_barrier();
    asm volatile("" ::: "memory");
    if (t + 3 < T) STAGE(t + 3);
    const u16* as = AsB + (t & 3) * 4096;
    const u16* bs = BsB + (t & 3) * 4096;
    s8v af[4], bf[2];
    int cc = lane >> 4;
#pragma unroll
    for (int i = 0; i < 4; i++) {
      int R = wm + i * 16 + (lane & 15);
      af[i] = *reinterpret_cast<const s8v*>(
          &as[R * 32 + (cc ^ ((R >> 1) & 3)) * 8]);
    }
#pragma unroll
    for (int i = 0; i < 2; i++) {
      int C = wn + i * 16 + (lane & 15);
      bf[i] = *reinterpret_cast<const s8v*>(
          &bs[C * 32 + (cc ^ ((C >> 1) & 3)) * 8]);
    }
    __builtin_amdgcn_s_setprio(1);
#pragma unroll
    for (int mi = 0; mi < 4; mi++)
#pragma unroll
      for (int ni = 0; ni < 2; ni++)
        acc[mi][ni] = __builtin_amdgcn_mfma_f32_16x16x32_bf16(
            af[mi], bf[ni], acc[mi][ni], 0, 0, 0);
    __builtin_amdgcn_s_setprio(0);
  }
#pragma unroll
  for (int mi = 0; mi < 4; mi++)
#pragma unroll
    for (int ni = 0; ni < 2; ni++)
#pragma unroll
      for (int r = 0; r < 4; r++) {
        int row = m0 + wm + mi * 16 + (lane >> 4) * 4 + r;
        int col = n0 + wn + ni * 16 + (lane & 15);
        epi<EP>(row, col, acc[mi][ni][r], g);
      }
}

// 2-buffer depth-1 variant (32KB total LDS) for occupancy-sensitive mixes.
template<int EP, int KV>
__device__ void gemm_2buf(const GP& g, u16* AsB, u16* BsB, int m0, int n0) {
  const int tid = threadIdx.x, lane = tid & 63, w = tid >> 6;
  const int wm = (w >> 2) * 64, wn = (w & 3) * 32;
  const int sr = tid >> 2, sc = (tid & 3) ^ ((sr >> 1) & 3);
  const u16* gA = g.A + (size_t)(m0 + sr) * g.lda + sc * 8;
  const u16* gB = g.B + (size_t)(n0 + sr) * KV + sc * 8;
  const int ls = tid * 8;

  f4v acc[4][2];
  f4v z4 = {0.f, 0.f, 0.f, 0.f};
#pragma unroll
  for (int a = 0; a < 4; a++) { acc[a][0] = z4; acc[a][1] = z4; }

  constexpr int T = KV / 32;
  auto STAGE = [&](int t) {
    int buf = (t & 1) * 4096;
    gl16(gA + t * 32, AsB + buf + ls);
    gl16(gB + t * 32, BsB + buf + ls);
  };
  STAGE(0);
#pragma unroll
  for (int t = 0; t < T; t++) {
    __syncthreads();  // drains vmcnt: buf[t&1] ready, buf[t&1^1] free
    if (t + 1 < T) STAGE(t + 1);
    const u16* as = AsB + (t & 1) * 4096;
    const u16* bs = BsB + (t & 1) * 4096;
    s8v af[4], bf[2];
    int cc = lane >> 4;
#pragma unroll
    for (int i = 0; i < 4; i++) {
      int R = wm + i * 16 + (lane & 15);
      af[i] = *reinterpret_cast<const s8v*>(
          &as[R * 32 + (cc ^ ((R >> 1) & 3)) * 8]);
    }
#pragma unroll
    for (int i = 0; i < 2; i++) {
      int C = wn + i * 16 + (lane & 15);
      bf[i] = *reinterpret_cast<const s8v*>(
          &bs[C * 32 + (cc ^ ((C >> 1) & 3)) * 8]);
    }
    __builtin_amdgcn_s_setprio(1);
#pragma unroll
    for (int mi = 0; mi < 4; mi++)
#pragma unroll
      for (int ni = 0; ni < 2; ni++)
        acc[mi][ni] = __builtin_amdgcn_mfma_f32_16x16x32_bf16(
            af[mi], bf[ni], acc[mi][ni], 0, 0, 0);
    __builtin_amdgcn_s_setprio(0);
  }
#pragma unroll
  for (int mi = 0; mi < 4; mi++)
#pragma unroll
    for (int ni = 0; ni < 2; ni++)
#pragma unroll
      for (int r = 0; r < 4; r++) {
        int row = m0 + wm + mi * 16 + (lane >> 4) * 4 + r;
        int col = n0 + wn + ni * 16 + (lane & 15);
        epi<EP>(row, col, acc[mi][ni][r], g);
      }
}

template<int EP, int KV>
__global__ __launch_bounds__(512, 4) void k_gemm(GP g) {
  __shared__ u16 As[4 * 4096], Bs[4 * 4096];
  int m0, n0;
  swz_tile(gridDim.x, gridDim.y, m0, n0);
  gemm_core<EP, KV>(g, As, Bs, m0, n0);
}

template<int EPa, int EPb, int KV>
__global__ __launch_bounds__(512, 4) void k_pair(GP a, GP b) {
  __shared__ u16 As[4 * 4096], Bs[4 * 4096];
  int m0, n0;
  swz_tile(gridDim.x, gridDim.y, m0, n0);
  if (blockIdx.z == 0) gemm_core<EPa, KV>(a, As, Bs, m0, n0);
  else gemm_core<EPb, KV>(b, As, Bs, m0, n0);
}

// ---------------- mixed dispatch: E/ctx-table GEMMs first, then cvtH -------
// 32KB LDS (2-buf GEMMs) -> 4 blocks/CU. GEMM tiles at grid front so they
// start immediately and finish inside the streaming phase (no tail).
// blocks [0,128): ge tiles  [128,144): gc tiles  [144,8336): H f32 -> H_bf
__global__ __launch_bounds__(512, 4) void k_mix(
    const float* __restrict__ src, u16* __restrict__ Hb, GP ge, GP gc) {
  __shared__ u16 S[16384];  // 32 KB: As 2x4096 | Bs 2x4096
  int id = blockIdx.x;
  if (id < 128) {
    gemm_2buf<0, 512>(ge, S, S + 8192, (id >> 4) * 128, (id & 15) * 128);
    return;
  }
  if (id < 144) {
    int t = id - 128;
    gemm_2buf<0, 128>(gc, S, S + 8192, (t >> 3) * 128, (t & 7) * 128);
    return;
  }
  size_t i = ((size_t)(id - 144) * 512 + threadIdx.x) * 8;
  float4 a = *reinterpret_cast<const float4*>(src + i);
  float4 b = *reinterpret_cast<const float4*>(src + i + 4);
  uint4 o = {pk(a.x, a.y), pk(a.z, a.w), pk(b.x, b.y), pk(b.z, b.w)};
  *reinterpret_cast<uint4*>(&Hb[i]) = o;  // fully contiguous 67MB write
}

// ---------------- fused z+new_h (z==0) + stop_h GEMM (z==1) -----------------
// z==0: two K=512 contractions flattened into ONE 32-step parity-interleaved
// loop with the 4-buf 3-deep counted-vmcnt pipeline (2 loads/thread/step).
__global__ __launch_bounds__(512, 4) void k_znp(
    const u16* __restrict__ sumh, const u16* __restrict__ sg,
    const u16* __restrict__ Wz, const u16* __restrict__ Wh,
    const float* __restrict__ E_z, const float* __restrict__ E_h, int ldg,
    const int* __restrict__ gidx, u16* __restrict__ newh, GP gs) {
  __shared__ u16 S[32768];  // 64 KB shared between the two block roles
  int m0, n0;
  swz_tile(gridDim.x, gridDim.y, m0, n0);
  if (blockIdx.z == 1) { gemm_core<3, 512>(gs, S, S + 16384, m0, n0); return; }
  const int tid = threadIdx.x, lane = tid & 63, w = tid >> 6;
  const int wm = (w >> 2) * 64, wn = (w & 3) * 32;

  const int sr = tid >> 2, sc = (tid & 3) ^ ((sr >> 1) & 3);
  const u16* gA[2] = {sumh + (size_t)(m0 + sr) * HDIM + sc * 8,
                      sg + (size_t)(m0 + sr) * HDIM + sc * 8};
  const u16* gB[2] = {Wz + (size_t)(n0 + sr) * HDIM + sc * 8,
                      Wh + (size_t)(n0 + sr) * HDIM + sc * 8};
  const int ls = tid * 8;
  u16* AsB = S;            // 4 bufs x 4096 u16
  u16* BsB = S + 16384;    // 4 bufs x 4096 u16
  auto STAGE = [&](int s) {
    int p = s & 1, k0 = (s >> 1) * 32;
    int buf = (s & 3) * 4096;
    gl16(gA[p] + k0, AsB + buf + ls);
    gl16(gB[p] + k0, BsB + buf + ls);
  };

  f4v az[4][2], ah[4][2];
  f4v z4 = {0.f, 0.f, 0.f, 0.f};
#pragma unroll
  for (int a = 0; a < 4; a++) {
    az[a][0] = z4; az[a][1] = z4; ah[a][0] = z4; ah[a][1] = z4;
  }

  STAGE(0); STAGE(1); STAGE(2);
#pragma unroll
  for (int s = 0; s < 32; s++) {
    if (s < 30) wait_vm<4>();
    else if (s == 30) wait_vm<2>();
    else wait_vm<0>();
    __builtin_amdgcn_s_barrier();
    asm volatile("" ::: "memory");
    if (s + 3 < 32) STAGE(s + 3);
    const u16* as = AsB + (s & 3) * 4096;
    const u16* bs = BsB + (s & 3) * 4096;
    s8v af[4], bf[2];
    int cc = lane >> 4;
#pragma unroll
    for (int i = 0; i < 4; i++) {
      int R = wm + i * 16 + (lane & 15);
      af[i] = *reinterpret_cast<const s8v*>(
          &as[R * 32 + (cc ^ ((R >> 1) & 3)) * 8]);
    }
#pragma unroll
    for (int i = 0; i < 2; i++) {
      int C = wn + i * 16 + (lane & 15);
      bf[i] = *reinterpret_cast<const s8v*>(
          &bs[C * 32 + (cc ^ ((C >> 1) & 3)) * 8]);
    }
    f4v (&acc)[4][2] = (s & 1) ? ah : az;  // s is compile-time (unrolled)
    __builtin_amdgcn_s_setprio(1);
#pragma unroll
    for (int mi = 0; mi < 4; mi++)
#pragma unroll
      for (int ni = 0; ni < 2; ni++)
        acc[mi][ni] = __builtin_amdgcn_mfma_f32_16x16x32_bf16(
            af[mi], bf[ni], acc[mi][ni], 0, 0, 0);
    __builtin_amdgcn_s_setprio(0);
  }
#pragma unroll
  for (int mi = 0; mi < 4; mi++)
#pragma unroll
    for (int r = 0; r < 4; r++) {
      int row = m0 + wm + mi * 16 + (lane >> 4) * 4 + r;
      int xid = gidx[row];
      const float* ez = E_z + (size_t)xid * ldg;
      const float* eh = E_h + (size_t)xid * ldg;
#pragma unroll
      for (int ni = 0; ni < 2; ni++) {
        int col = n0 + wn + ni * 16 + (lane & 15);
        float zv = sigm(az[mi][ni][r] + ez[col]);
        float pre = tanhf(ah[mi][ni][r] + eh[col]);
        float sh = bu2f(sumh[(size_t)row * HDIM + col]);
        newh[(size_t)row * HDIM + col] = f2bu((1.f - zv) * sh + zv * pre);
      }
    }
}

// ---------------- fused gather: 4 nodes/block, 64 thr/node, uint4 loads -----
__global__ __launch_bounds__(256) void k_gsr(
    const u16* __restrict__ Hb, const u16* __restrict__ R2,
    const float* __restrict__ E_r, int ldg, const int* __restrict__ x_ids,
    const int* __restrict__ nei_idx, const int* __restrict__ nei_mask,
    const int* __restrict__ o_idx, const int* __restrict__ o_mask,
    u16* __restrict__ sum_h_bf, u16* __restrict__ sg_bf,
    u16* __restrict__ cur_o_bf) {
  int t = threadIdx.x;
  int nd = t >> 6, lane = t & 63;
  int n = blockIdx.x * 4 + nd;
  __shared__ int sidx[4][NB], smsk[4][NB], soid[4][NB], somk[4][NB];
  __shared__ int sx[4];
  if (t < 60) {
    int nn = t / 15, k = t - nn * 15;
    size_t gofs = (size_t)(blockIdx.x * 4 + nn) * NB + k;
    sidx[nn][k] = nei_idx[gofs];
    smsk[nn][k] = nei_mask[gofs];
  } else if (t >= 64 && t < 124) {
    int tt = t - 64;
    int nn = tt / 15, k = tt - nn * 15;
    size_t gofs = (size_t)(blockIdx.x * 4 + nn) * NB + k;
    soid[nn][k] = o_idx[gofs];
    somk[nn][k] = o_mask[gofs];
  } else if (t >= 128 && t < 132) {
    sx[t - 128] = x_ids[blockIdx.x * 4 + (t - 128)];
  }
  __syncthreads();
  int c = lane * 8;
  const float* er = E_r + (size_t)sx[nd] * ldg + c;
  float4 e0 = *reinterpret_cast<const float4*>(er);
  float4 e1 = *reinterpret_cast<const float4*>(er + 4);
  float ev[8] = {e0.x, e0.y, e0.z, e0.w, e1.x, e1.y, e1.z, e1.w};
  float s[8], gg[8], oo[8];
#pragma unroll
  for (int i = 0; i < 8; i++) { s[i] = 0.f; gg[i] = 0.f; oo[i] = 0.f; }
#pragma unroll
  for (int k = 0; k < NB; k++) {
    if (smsk[nd][k]) {
      size_t rb = (size_t)sidx[nd][k] * HDIM + c;
      uint4 hv = *reinterpret_cast<const uint4*>(Hb + rb);
      uint4 rv = *reinterpret_cast<const uint4*>(R2 + rb);
      u32 ha[4] = {hv.x, hv.y, hv.z, hv.w};
      u32 ra[4] = {rv.x, rv.y, rv.z, rv.w};
#pragma unroll
      for (int p = 0; p < 4; p++) {
        float h0 = bu2f((u16)ha[p]), h1 = bu2f((u16)(ha[p] >> 16));
        s[p * 2] += h0; s[p * 2 + 1] += h1;
        gg[p * 2] += sigm(bu2f((u16)ra[p]) + ev[p * 2]) * h0;
        gg[p * 2 + 1] += sigm(bu2f((u16)(ra[p] >> 16)) + ev[p * 2 + 1]) * h1;
      }
    }
    if (somk[nd][k]) {
      uint4 ov = *reinterpret_cast<const uint4*>(
          Hb + (size_t)soid[nd][k] * HDIM + c);
      u32 oa[4] = {ov.x, ov.y, ov.z, ov.w};
#pragma unroll
      for (int p = 0; p < 4; p++) {
        oo[p * 2] += bu2f((u16)oa[p]);
        oo[p * 2 + 1] += bu2f((u16)(oa[p] >> 16));
      }
    }
  }
  size_t b = (size_t)n * HDIM + c;
  uint4 ps = {pk(s[0], s[1]), pk(s[2], s[3]), pk(s[4], s[5]), pk(s[6], s[7])};
  uint4 pg = {pk(gg[0], gg[1]), pk(gg[2], gg[3]), pk(gg[4], gg[5]), pk(gg[6], gg[7])};
  uint4 po = {pk(oo[0], oo[1]), pk(oo[2], oo[3]), pk(oo[4], oo[5]), pk(oo[6], oo[7])};
  *reinterpret_cast<uint4*>(&sum_h_bf[b]) = ps;
  *reinterpret_cast<uint4*>(&sg_bf[b]) = pg;
  *reinterpret_cast<uint4*>(&cur_o_bf[b]) = po;
}

// ---------------- word GEMM (z==0) + stop scores (z==1) ---------------------
__global__ __launch_bounds__(512, 4) void k_wordstop(
    GP wgp, const u16* __restrict__ shid, const float* __restrict__ Uo_w,
    const float* __restrict__ Uo_b, float* __restrict__ out) {
  __shared__ u16 As[4 * 4096], Bs[4 * 4096];
  if (blockIdx.z == 0) {
    int m0, n0;
    swz_tile(gridDim.x, gridDim.y, m0, n0);
    gemm_core<0, 512>(wgp, As, Bs, m0, n0);
    return;
  }
  int b = blockIdx.y * gridDim.x + blockIdx.x;  // 0..1023
  int wv = threadIdx.x >> 6, lane = threadIdx.x & 63;
#pragma unroll
  for (int i = 0; i < 2; i++) {
    int n = b * 16 + wv * 2 + i;
    const u16* row = shid + (size_t)n * HDIM + lane * 8;
    const float* uw = Uo_w + lane * 8;
    uint4 v = *reinterpret_cast<const uint4*>(row);
    float4 u0 = *reinterpret_cast<const float4*>(uw);
    float4 u1 = *reinterpret_cast<const float4*>(uw + 4);
    float s = bu2f((u16)v.x) * u0.x + bu2f((u16)(v.x >> 16)) * u0.y +
              bu2f((u16)v.y) * u0.z + bu2f((u16)(v.y >> 16)) * u0.w +
              bu2f((u16)v.z) * u1.x + bu2f((u16)(v.z >> 16)) * u1.y +
              bu2f((u16)v.w) * u1.z + bu2f((u16)(v.w >> 16)) * u1.w;
#pragma unroll
    for (int off = 32; off; off >>= 1) s += __shfl_xor(s, off, 64);
    if (lane == 0) out[(size_t)n * 1025 + 1024] = s + Uo_b[0];
  }
}

// ---------------- host ----------------
extern "C" void kernel_launch(void* const* d_in, const int* in_sizes, int n_in,
                              void* d_out, int out_size, void* d_ws, size_t ws_size,
                              hipStream_t stream) {
  const int* x_ids = (const int*)d_in[0];
  const int* contexts = (const int*)d_in[1];
  const int* nei_idx = (const int*)d_in[2];
  const int* nei_mask = (const int*)d_in[3];
  const int* o_idx = (const int*)d_in[4];
  const int* o_mask = (const int*)d_in[5];
  const float* H_msg = (const float*)d_in[6];
  const float* xtree = (const float*)d_in[7];
  const float* emb = (const float*)d_in[8];
  const float* Wz_w = (const float*)d_in[9];  const float* Wz_b = (const float*)d_in[10];
  const float* Wr_w = (const float*)d_in[11]; const float* Wr_b = (const float*)d_in[12];
  const float* Ur_w = (const float*)d_in[13];
  const float* Wh_w = (const float*)d_in[14]; const float* Wh_b = (const float*)d_in[15];
  const float* W_w  = (const float*)d_in[16]; const float* W_b  = (const float*)d_in[17];
  const float* Wo_w = (const float*)d_in[18]; const float* Wo_b = (const float*)d_in[19];
  const float* Ui_w = (const float*)d_in[20]; const float* Ui_b = (const float*)d_in[21];
  const float* U_w  = (const float*)d_in[22]; const float* U_b  = (const float*)d_in[23];
  const float* Uo_w = (const float*)d_in[24]; const float* Uo_b = (const float*)d_in[25];
  float* out = (float*)d_out;
  const int M = 65536;

  char* base = (char*)d_ws;
  size_t ofs = 0;
  auto alloc = [&](size_t bytes) -> char* {
    char* p = base + ofs;
    ofs = (ofs + bytes + 255) & ~(size_t)255;
    return p;
  };
  u16* wcat  = (u16*)alloc((size_t)2048 * 512 * 2);
  u16* wz_h  = (u16*)alloc(512 * 512 * 2);
  u16* wh_h  = (u16*)alloc(512 * 512 * 2);
  u16* ui_h  = (u16*)alloc(512 * 512 * 2);
  u16* ur    = (u16*)alloc(512 * 512 * 2);
  u16* w_n   = (u16*)alloc(512 * 512 * 2);
  u16* u_n   = (u16*)alloc(512 * 512 * 2);
  u16* ccat  = (u16*)alloc(1024 * 128 * 2);
  u16* wo    = (u16*)alloc(1024 * 512 * 2);
  u16* emb_bf = (u16*)alloc(1024 * 512 * 2);
  u16* xt_bf  = (u16*)alloc(256 * 128 * 2);
  float* ebias = (float*)alloc(2048 * 4);
  float* cbias = (float*)alloc(1024 * 4);
  float* E_cat = (float*)alloc((size_t)1024 * 2048 * 4);
  float* C_cat = (float*)alloc((size_t)256 * 1024 * 4);
  u16* H_bf = (u16*)alloc((size_t)M * HDIM * 2);
  u16* R2   = (u16*)alloc((size_t)M * HDIM * 2);
  u16* sum_h_bf = (u16*)alloc((size_t)NNODE * HDIM * 2);
  u16* cur_o_bf = (u16*)alloc((size_t)NNODE * HDIM * 2);
  u16* sg_bf    = (u16*)alloc((size_t)NNODE * HDIM * 2);
  u16* newh_bf  = (u16*)alloc((size_t)NNODE * HDIM * 2);
  u16* whid_bf  = (u16*)alloc((size_t)NNODE * HDIM * 2);
  u16* stoph_bf = (u16*)alloc((size_t)NNODE * HDIM * 2);
  u16* shid_bf  = (u16*)alloc((size_t)NNODE * HDIM * 2);

  k_cvt_all<<<dim3(256, 21), dim3(256), 0, stream>>>(
      Wz_w, Wr_w, Wh_w, Ui_w, Ur_w, W_w, U_w, Wo_w, emb, xtree,
      Wz_b, Wr_b, Wh_b, Ui_b, W_b, U_b,
      wcat, wz_h, wh_h, ui_h, ur, w_n, u_n, ccat, wo, emb_bf, xt_bf,
      ebias, cbias);

  // table GEMMs (front of grid) || cvtH streaming (contiguous writes)
  GP ge{emb_bf, wcat, 512, 512, nullptr, 0, nullptr, ebias, nullptr,
        E_cat, nullptr, 2048};
  GP gc{xt_bf, ccat, 128, 128, nullptr, 0, nullptr, cbias, nullptr,
        C_cat, nullptr, 1024};
  k_mix<<<dim3(8336), dim3(512), 0, stream>>>(H_msg, H_bf, ge, gc);

  // R2 = H @ Ur^T for ALL messages -> separate contiguous array
  GP gr{H_bf, ur, 512, 512, nullptr, 0, nullptr, nullptr, nullptr,
        nullptr, R2, 512};
  k_gemm<4, 512><<<dim3(4, 512), dim3(512), 0, stream>>>(gr);

  // fused gather: sum_h, sg = sum sigmoid(r2+E_r)*h, cur_o
  k_gsr<<<dim3(NNODE / 4), dim3(256), 0, stream>>>(
      H_bf, R2, E_cat + 512, 2048, x_ids, nei_idx, nei_mask, o_idx, o_mask,
      sum_h_bf, sg_bf, cur_o_bf);

  // z+new_h (z==0) and stop_h (z==1) in one dispatch
  GP gs{cur_o_bf, ui_h, 512, 512, E_cat + 1536, 2048, x_ids, nullptr, nullptr,
        nullptr, stoph_bf, 512};
  k_znp<<<dim3(4, 128, 2), dim3(512), 0, stream>>>(
      sum_h_bf, sg_bf, wz_h, wh_h, E_cat, E_cat + 1024, 2048, x_ids,
      newh_bf, gs);

  // w_hid + s_hid paired (both EP3)
  GP gw{newh_bf, w_n, 512, 512, C_cat, 1024, contexts, nullptr, nullptr,
        nullptr, whid_bf, 512};
  GP gu{stoph_bf, u_n, 512, 512, C_cat + 512, 1024, contexts, nullptr, nullptr,
        nullptr, shid_bf, 512};
  k_pair<3, 3, 512><<<dim3(4, 128, 2), dim3(512), 0, stream>>>(gw, gu);

  // word scores (z==0) + stop scores (z==1)
  GP gword{whid_bf, wo, 512, 512, nullptr, 0, nullptr, Wo_b, nullptr,
           out, nullptr, 1025};
  k_wordstop<<<dim3(8, 128, 2), dim3(512), 0, stream>>>(
      gword, shid_bf, Uo_w, Uo_b, out);
}